// Round 1
// baseline (207.292 us; speedup 1.0000x reference)
//
#include <hip/hip_runtime.h>
#include <math.h>

static constexpr int Bq  = 8;
static constexpr int DIN = 1024;
static constexpr int TTT = 2048;
static constexpr int KCB = 8192;

static constexpr int NCH = 64;    // VQ chunks
static constexpr int CPC = 128;   // codes per chunk (NCH*CPC == KCB)

// d_out layout (floats)
static constexpr size_t OUT_OFS  = 0;
static constexpr size_t LOSS_OFS = (size_t)Bq * DIN * TTT;      // 16777216 (16 zeros)
static constexpr size_t IDX_OFS  = LOSS_OFS + 16;               // 16777232 (B*T)
static constexpr size_t ZE_OFS   = IDX_OFS + (size_t)Bq * TTT;  // 16793616 (B*8*T)

// ws layout (float offsets)
static constexpr size_t WS_CBN  = 0;          // 8192*8 normalized codebook
static constexpr size_t WS_C2   = 65536;      // 8192 0.5*||c_n||^2
static constexpr size_t WS_WT   = 73728;      // 1024*8 transposed w_in
static constexpr size_t WS_ENC  = 81920;      // 16384*8 z_e row-major [row][cd]
static constexpr size_t WS_PART = 212992;     // float[NCH][16384] chunk-min scores
static constexpr size_t WS_IDXI = WS_PART + (size_t)NCH * 16384; // 16384 ints

// Shared helpers: MUST be the bit-identical fp DAG in k2_scan and k2b_argmin
// so the recovery pass reproduces the exact min value / ordering.
__device__ __forceinline__ void load_enc_neg_norm(const float* __restrict__ ws,
                                                  int r, float4& ma, float4& mb) {
  const float4* ep = (const float4*)(ws + WS_ENC + (size_t)r * 8);
  float4 a = ep[0], c = ep[1];
  float n2 = 0.f;
  n2 = fmaf(a.x, a.x, n2); n2 = fmaf(a.y, a.y, n2);
  n2 = fmaf(a.z, a.z, n2); n2 = fmaf(a.w, a.w, n2);
  n2 = fmaf(c.x, c.x, n2); n2 = fmaf(c.y, c.y, n2);
  n2 = fmaf(c.z, c.z, n2); n2 = fmaf(c.w, c.w, n2);
  float dn = fmaxf(sqrtf(n2), 1e-12f);
  ma.x = -(a.x / dn); ma.y = -(a.y / dn);
  ma.z = -(a.z / dn); ma.w = -(a.w / dn);
  mb.x = -(c.x / dn); mb.y = -(c.y / dn);
  mb.z = -(c.z / dn); mb.w = -(c.w / dn);
}

__device__ __forceinline__ float score8(const float4& ma, const float4& mb,
                                        const float4& c0, const float4& c1, float cc) {
  // score = 0.5*||c_n||^2 - enc_n . c_n   (monotone transform of reference dist)
  float s = fmaf(ma.x, c0.x, cc);
  s = fmaf(ma.y, c0.y, s); s = fmaf(ma.z, c0.z, s); s = fmaf(ma.w, c0.w, s);
  s = fmaf(mb.x, c1.x, s); s = fmaf(mb.y, c1.y, s);
  s = fmaf(mb.z, c1.z, s); s = fmaf(mb.w, c1.w, s);
  return s;
}

// ---------------- K0: normalize codebook, transpose w_in, zero losses ----------
__global__ __launch_bounds__(256) void k0_prep(
    const float* __restrict__ w_in, const float* __restrict__ codebook,
    float* __restrict__ ws, float* __restrict__ out)
{
  int tid = blockIdx.x * 256 + threadIdx.x;
  if (tid < KCB) {
    const float4* cp = (const float4*)(codebook + (size_t)tid * 8);
    float4 a = cp[0], b = cp[1];
    float v[8] = {a.x, a.y, a.z, a.w, b.x, b.y, b.z, b.w};
    float n2 = 0.f;
#pragma unroll
    for (int o = 0; o < 8; o++) n2 = fmaf(v[o], v[o], n2);
    float dn = fmaxf(sqrtf(n2), 1e-12f);
    float u[8];
    float s2 = 0.f;
#pragma unroll
    for (int o = 0; o < 8; o++) { u[o] = v[o] / dn; s2 = fmaf(u[o], u[o], s2); }
    float4* wp = (float4*)(ws + WS_CBN + (size_t)tid * 8);
    wp[0] = make_float4(u[0], u[1], u[2], u[3]);
    wp[1] = make_float4(u[4], u[5], u[6], u[7]);
    ws[WS_C2 + tid] = 0.5f * s2;  // folded half-norm for score = 0.5*c2 - dot
  } else if (tid < KCB + DIN) {
    int d = tid - KCB;
#pragma unroll
    for (int o = 0; o < 8; o++) ws[WS_WT + (size_t)d * 8 + o] = w_in[(size_t)o * DIN + d];
  } else if (tid < KCB + DIN + 16) {
    out[LOSS_OFS + (tid - KCB - DIN)] = 0.f;  // commit_loss + codebook_loss zeros
  }
}

// ---------------- K1: z_e = w_in @ z + b_in  (HBM-bound, 64 MiB read) ----------
__global__ __launch_bounds__(512) void k1_proj_in(
    const float* __restrict__ z, const float* __restrict__ b_in,
    float* __restrict__ ws, float* __restrict__ out)
{
  __shared__ __align__(16) float lds[16384];  // 64 KB: wt staging, then partial[32][8][64]
  int tid = threadIdx.x;
  int bx = blockIdx.x;
  int b = bx >> 5;
  int t0 = (bx & 31) << 6;
  {
    const float4* src = (const float4*)(ws + WS_WT);
    float4* dst = (float4*)lds;
#pragma unroll
    for (int i = 0; i < 4; i++) dst[tid + 512 * i] = src[tid + 512 * i];
  }
  __syncthreads();
  int tt = tid & 15;
  int dg = tid >> 4;
  const float* zb = z + (size_t)b * DIN * TTT + t0 + (tt << 2);
  float4 acc[8];
#pragma unroll
  for (int o = 0; o < 8; o++) acc[o] = make_float4(0.f, 0.f, 0.f, 0.f);
  int dbase = dg << 5;
  const float4* wl = (const float4*)lds;
#pragma unroll 8
  for (int i = 0; i < 32; i++) {
    int d = dbase + i;
    float4 zv = *(const float4*)(zb + (size_t)d * TTT);
    float4 w0 = wl[d * 2 + 0];
    float4 w1 = wl[d * 2 + 1];
#define ACC1(o, wsc)                                    \
    acc[o].x = fmaf(wsc, zv.x, acc[o].x);               \
    acc[o].y = fmaf(wsc, zv.y, acc[o].y);               \
    acc[o].z = fmaf(wsc, zv.z, acc[o].z);               \
    acc[o].w = fmaf(wsc, zv.w, acc[o].w);
    ACC1(0, w0.x) ACC1(1, w0.y) ACC1(2, w0.z) ACC1(3, w0.w)
    ACC1(4, w1.x) ACC1(5, w1.y) ACC1(6, w1.z) ACC1(7, w1.w)
#undef ACC1
  }
  __syncthreads();
  {
    float4* pl = (float4*)lds;
#pragma unroll
    for (int o = 0; o < 8; o++) pl[dg * 128 + o * 16 + tt] = acc[o];
  }
  __syncthreads();
  int o = tid >> 6;
  int t = tid & 63;
  float s = 0.f;
#pragma unroll
  for (int g = 0; g < 32; g++) s += lds[g * 512 + o * 64 + t];
  s += b_in[o];
  out[ZE_OFS + ((size_t)b * 8 + o) * TTT + t0 + t] = s;
  ws[WS_ENC + ((size_t)(b * TTT + t0 + t)) * 8 + o] = s;
}

// ---------------- K2: VQ min-scan. grid 1024 = rowblocks(16) x chunks(64)
// block 256, R=4 rows/thread, CPC=128 codes/chunk staged in LDS.
// Tracks ONLY the per-(row,chunk) min score (no index): 2 codes per step,
// v_min3_f32 folds both scores + running best into one instruction.
// Index recovery happens in k2b_argmin by rescanning the winning chunk with
// the bit-identical fp DAG (score8/load_enc_neg_norm shared above).
__global__ __launch_bounds__(256) void k2_scan(float* __restrict__ ws)
{
  __shared__ __align__(16) float4 scb[CPC * 2];
  __shared__ float sch[CPC];
  int tid = threadIdx.x;
  int rb = blockIdx.x >> 6;  // 16 rowblocks of 1024 rows
  int ch = blockIdx.x & 63;  // 64 chunks
  int k0 = ch << 7;          // CPC codes per chunk
  if (tid < CPC) {
    const float4* src = (const float4*)(ws + WS_CBN + (size_t)(k0 + tid) * 8);
    scb[tid * 2]     = src[0];
    scb[tid * 2 + 1] = src[1];
    sch[tid] = ws[WS_C2 + k0 + tid];
  }
  int rbase = (rb << 10) + tid;  // rows rbase + j*256, j<4

  float4 m0a, m0b, m1a, m1b, m2a, m2b, m3a, m3b;
  load_enc_neg_norm(ws, rbase,       m0a, m0b);
  load_enc_neg_norm(ws, rbase + 256, m1a, m1b);
  load_enc_neg_norm(ws, rbase + 512, m2a, m2b);
  load_enc_neg_norm(ws, rbase + 768, m3a, m3b);
  float b0 = 3.4e38f, b1 = 3.4e38f, b2 = 3.4e38f, b3 = 3.4e38f;

  __syncthreads();
#pragma unroll 2
  for (int k = 0; k < CPC; k += 2) {
    float4 c00 = scb[2 * k + 0];
    float4 c01 = scb[2 * k + 1];
    float4 c10 = scb[2 * k + 2];
    float4 c11 = scb[2 * k + 3];
    float ca = sch[k];
    float cb = sch[k + 1];
#define STEP2(ma, mb, bj) {                                                   \
    float s0 = score8(ma, mb, c00, c01, ca);                                  \
    float s1 = score8(ma, mb, c10, c11, cb);                                  \
    asm("v_min3_f32 %0, %1, %2, %3" : "=v"(bj) : "v"(bj), "v"(s0), "v"(s1)); }
    STEP2(m0a, m0b, b0)
    STEP2(m1a, m1b, b1)
    STEP2(m2a, m2b, b2)
    STEP2(m3a, m3b, b3)
#undef STEP2
  }
  float* part = ws + WS_PART + (size_t)ch * 16384 + rbase;
  part[0]   = b0;
  part[256] = b1;
  part[512] = b2;
  part[768] = b3;
}

// ---------------- K2b: per row, min over chunk-mins (first-min chunk), then
// rescan that chunk's 128 codes with identical arithmetic to recover the index
// (strict < => first minimum, matching reference argmax(-dist) tie order).
__global__ __launch_bounds__(256) void k2b_argmin(float* __restrict__ ws, float* __restrict__ out)
{
  int r = blockIdx.x * 256 + threadIdx.x;
  const float* part = ws + WS_PART;
  float m = 3.4e38f;
  int cbest = 0;
#pragma unroll 8
  for (int ch = 0; ch < NCH; ch++) {
    float p = part[(size_t)ch * 16384 + r];
    if (p < m) { m = p; cbest = ch; }  // ascending chunk => first min chunk
  }
  float4 ma, mb;
  load_enc_neg_norm(ws, r, ma, mb);
  int base = cbest << 7;
  float best = 3.4e38f;
  int bi = 0;
#pragma unroll 4
  for (int k = 0; k < CPC; k++) {
    const float4* cp = (const float4*)(ws + WS_CBN + (size_t)(base + k) * 8);
    float4 c0 = cp[0], c1 = cp[1];
    float cc = ws[WS_C2 + base + k];
    float s = score8(ma, mb, c0, c1, cc);
    if (s < best) { best = s; bi = base + k; }  // first min within chunk
  }
  out[IDX_OFS + r] = (float)bi;
  ((int*)(ws + WS_IDXI))[r] = bi;
}

// ---------------- K3: out = w_out @ codebook[idx] + b_out (HBM write-bound) -----
__global__ __launch_bounds__(256) void k3_proj_out(
    const float* __restrict__ codebook, const float* __restrict__ w_out,
    const float* __restrict__ b_out, const float* __restrict__ ws,
    float* __restrict__ out)
{
  int bx = blockIdx.x;
  int b = bx >> 7;
  int th = (bx >> 6) & 1;
  int dt = bx & 63;
  int tid = threadIdx.x;
  int t = (th << 10) + (tid << 2);
  const int* idxp = (const int*)(ws + WS_IDXI);
  int4 id = *(const int4*)(idxp + b * TTT + t);
  const float4* cbp = (const float4*)codebook;
  float4 c00 = cbp[(size_t)id.x * 2], c01 = cbp[(size_t)id.x * 2 + 1];
  float4 c10 = cbp[(size_t)id.y * 2], c11 = cbp[(size_t)id.y * 2 + 1];
  float4 c20 = cbp[(size_t)id.z * 2], c21 = cbp[(size_t)id.z * 2 + 1];
  float4 c30 = cbp[(size_t)id.w * 2], c31 = cbp[(size_t)id.w * 2 + 1];
  int d0 = dt << 4;
#pragma unroll 4
  for (int dd = 0; dd < 16; dd++) {
    int d = d0 + dd;
    const float* wr = w_out + (size_t)d * 8;
    float w0 = wr[0], w1 = wr[1], w2 = wr[2], w3 = wr[3];
    float w4 = wr[4], w5 = wr[5], w6 = wr[6], w7 = wr[7];
    float bb = b_out[d];
#define DOT8(lo, hi)                                                          \
    fmaf(w7, hi.w, fmaf(w6, hi.z, fmaf(w5, hi.y, fmaf(w4, hi.x,              \
    fmaf(w3, lo.w, fmaf(w2, lo.z, fmaf(w1, lo.y, fmaf(w0, lo.x, bb))))))))
    float4 r;
    r.x = DOT8(c00, c01);
    r.y = DOT8(c10, c11);
    r.z = DOT8(c20, c21);
    r.w = DOT8(c30, c31);
#undef DOT8
    *(float4*)(out + OUT_OFS + ((size_t)b * DIN + d) * TTT + t) = r;
  }
}

extern "C" void kernel_launch(void* const* d_in, const int* in_sizes, int n_in,
                              void* d_out, int out_size, void* d_ws, size_t ws_size,
                              hipStream_t stream) {
  const float* z        = (const float*)d_in[0];
  const float* w_in     = (const float*)d_in[1];
  const float* b_in     = (const float*)d_in[2];
  const float* w_out    = (const float*)d_in[3];
  const float* b_out    = (const float*)d_in[4];
  const float* codebook = (const float*)d_in[5];
  float* out = (float*)d_out;
  float* ws  = (float*)d_ws;

  k0_prep<<<dim3(37), dim3(256), 0, stream>>>(w_in, codebook, ws, out);
  k1_proj_in<<<dim3(256), dim3(512), 0, stream>>>(z, b_in, ws, out);
  k2_scan<<<dim3(1024), dim3(256), 0, stream>>>(ws);
  k2b_argmin<<<dim3(64), dim3(256), 0, stream>>>(ws, out);
  k3_proj_out<<<dim3(1024), dim3(256), 0, stream>>>(codebook, w_out, b_out, ws, out);
}

// Round 2
// 183.590 us; speedup vs baseline: 1.1291x; 1.1291x over previous
//
#include <hip/hip_runtime.h>
#include <math.h>

static constexpr int Bq  = 8;
static constexpr int DIN = 1024;
static constexpr int TTT = 2048;
static constexpr int KCB = 8192;

static constexpr int NCH = 64;    // VQ chunks
static constexpr int CPC = 128;   // codes per chunk (NCH*CPC == KCB)

// d_out layout (floats)
static constexpr size_t OUT_OFS  = 0;
static constexpr size_t LOSS_OFS = (size_t)Bq * DIN * TTT;      // 16777216 (16 zeros)
static constexpr size_t IDX_OFS  = LOSS_OFS + 16;               // 16777232 (B*T)
static constexpr size_t ZE_OFS   = IDX_OFS + (size_t)Bq * TTT;  // 16793616 (B*8*T)

// ws layout (float offsets)
static constexpr size_t WS_CBN  = 0;          // 8192*8 normalized codebook
static constexpr size_t WS_C2   = 65536;      // 8192 0.5*||c_n||^2
static constexpr size_t WS_WT   = 73728;      // 1024*8 transposed w_in
static constexpr size_t WS_ENC  = 81920;      // 16384*8 z_e row-major [row][cd]
static constexpr size_t WS_PART = 212992;     // float[NCH][16384] chunk-min scores
static constexpr size_t WS_IDXI = WS_PART + (size_t)NCH * 16384; // 16384 ints

// Shared helpers: MUST be the bit-identical fp DAG in k2_scan and k2b_argmin
// so the recovery pass reproduces the exact min value / ordering.
__device__ __forceinline__ void load_enc_neg_norm(const float* __restrict__ ws,
                                                  int r, float4& ma, float4& mb) {
  const float4* ep = (const float4*)(ws + WS_ENC + (size_t)r * 8);
  float4 a = ep[0], c = ep[1];
  float n2 = 0.f;
  n2 = fmaf(a.x, a.x, n2); n2 = fmaf(a.y, a.y, n2);
  n2 = fmaf(a.z, a.z, n2); n2 = fmaf(a.w, a.w, n2);
  n2 = fmaf(c.x, c.x, n2); n2 = fmaf(c.y, c.y, n2);
  n2 = fmaf(c.z, c.z, n2); n2 = fmaf(c.w, c.w, n2);
  float dn = fmaxf(sqrtf(n2), 1e-12f);
  ma.x = -(a.x / dn); ma.y = -(a.y / dn);
  ma.z = -(a.z / dn); ma.w = -(a.w / dn);
  mb.x = -(c.x / dn); mb.y = -(c.y / dn);
  mb.z = -(c.z / dn); mb.w = -(c.w / dn);
}

__device__ __forceinline__ float score8(const float4& ma, const float4& mb,
                                        const float4& c0, const float4& c1, float cc) {
  // score = 0.5*||c_n||^2 - enc_n . c_n   (monotone transform of reference dist)
  float s = fmaf(ma.x, c0.x, cc);
  s = fmaf(ma.y, c0.y, s); s = fmaf(ma.z, c0.z, s); s = fmaf(ma.w, c0.w, s);
  s = fmaf(mb.x, c1.x, s); s = fmaf(mb.y, c1.y, s);
  s = fmaf(mb.z, c1.z, s); s = fmaf(mb.w, c1.w, s);
  return s;
}

// ---------------- K0: normalize codebook, transpose w_in, zero losses ----------
__global__ __launch_bounds__(256) void k0_prep(
    const float* __restrict__ w_in, const float* __restrict__ codebook,
    float* __restrict__ ws, float* __restrict__ out)
{
  int tid = blockIdx.x * 256 + threadIdx.x;
  if (tid < KCB) {
    const float4* cp = (const float4*)(codebook + (size_t)tid * 8);
    float4 a = cp[0], b = cp[1];
    float v[8] = {a.x, a.y, a.z, a.w, b.x, b.y, b.z, b.w};
    float n2 = 0.f;
#pragma unroll
    for (int o = 0; o < 8; o++) n2 = fmaf(v[o], v[o], n2);
    float dn = fmaxf(sqrtf(n2), 1e-12f);
    float u[8];
    float s2 = 0.f;
#pragma unroll
    for (int o = 0; o < 8; o++) { u[o] = v[o] / dn; s2 = fmaf(u[o], u[o], s2); }
    float4* wp = (float4*)(ws + WS_CBN + (size_t)tid * 8);
    wp[0] = make_float4(u[0], u[1], u[2], u[3]);
    wp[1] = make_float4(u[4], u[5], u[6], u[7]);
    ws[WS_C2 + tid] = 0.5f * s2;  // folded half-norm for score = 0.5*c2 - dot
  } else if (tid < KCB + DIN) {
    int d = tid - KCB;
#pragma unroll
    for (int o = 0; o < 8; o++) ws[WS_WT + (size_t)d * 8 + o] = w_in[(size_t)o * DIN + d];
  } else if (tid < KCB + DIN + 16) {
    out[LOSS_OFS + (tid - KCB - DIN)] = 0.f;  // commit_loss + codebook_loss zeros
  }
}

// ---------------- K1: z_e = w_in @ z + b_in  (HBM-bound, 64 MiB read) ----------
__global__ __launch_bounds__(512) void k1_proj_in(
    const float* __restrict__ z, const float* __restrict__ b_in,
    float* __restrict__ ws, float* __restrict__ out)
{
  __shared__ __align__(16) float lds[16384];  // 64 KB: wt staging, then partial[32][8][64]
  int tid = threadIdx.x;
  int bx = blockIdx.x;
  int b = bx >> 5;
  int t0 = (bx & 31) << 6;
  {
    const float4* src = (const float4*)(ws + WS_WT);
    float4* dst = (float4*)lds;
#pragma unroll
    for (int i = 0; i < 4; i++) dst[tid + 512 * i] = src[tid + 512 * i];
  }
  __syncthreads();
  int tt = tid & 15;
  int dg = tid >> 4;
  const float* zb = z + (size_t)b * DIN * TTT + t0 + (tt << 2);
  float4 acc[8];
#pragma unroll
  for (int o = 0; o < 8; o++) acc[o] = make_float4(0.f, 0.f, 0.f, 0.f);
  int dbase = dg << 5;
  const float4* wl = (const float4*)lds;
#pragma unroll 8
  for (int i = 0; i < 32; i++) {
    int d = dbase + i;
    float4 zv = *(const float4*)(zb + (size_t)d * TTT);
    float4 w0 = wl[d * 2 + 0];
    float4 w1 = wl[d * 2 + 1];
#define ACC1(o, wsc)                                    \
    acc[o].x = fmaf(wsc, zv.x, acc[o].x);               \
    acc[o].y = fmaf(wsc, zv.y, acc[o].y);               \
    acc[o].z = fmaf(wsc, zv.z, acc[o].z);               \
    acc[o].w = fmaf(wsc, zv.w, acc[o].w);
    ACC1(0, w0.x) ACC1(1, w0.y) ACC1(2, w0.z) ACC1(3, w0.w)
    ACC1(4, w1.x) ACC1(5, w1.y) ACC1(6, w1.z) ACC1(7, w1.w)
#undef ACC1
  }
  __syncthreads();
  {
    float4* pl = (float4*)lds;
#pragma unroll
    for (int o = 0; o < 8; o++) pl[dg * 128 + o * 16 + tt] = acc[o];
  }
  __syncthreads();
  int o = tid >> 6;
  int t = tid & 63;
  float s = 0.f;
#pragma unroll
  for (int g = 0; g < 32; g++) s += lds[g * 512 + o * 64 + t];
  s += b_in[o];
  out[ZE_OFS + ((size_t)b * 8 + o) * TTT + t0 + t] = s;
  ws[WS_ENC + ((size_t)(b * TTT + t0 + t)) * 8 + o] = s;
}

// ---------------- K2: VQ min-scan. grid 1024 = rowblocks(16) x chunks(64)
// block 256, R=4 rows/thread, CPC=128 codes/chunk staged in LDS.
// Tracks ONLY the per-(row,chunk) min score (no index): 2 codes per step,
// v_min3_f32 folds both scores + running best into one instruction.
// Index recovery happens in k2b_argmin by rescanning the winning chunk with
// the bit-identical fp DAG (score8/load_enc_neg_norm shared above).
__global__ __launch_bounds__(256) void k2_scan(float* __restrict__ ws)
{
  __shared__ __align__(16) float4 scb[CPC * 2];
  __shared__ float sch[CPC];
  int tid = threadIdx.x;
  int rb = blockIdx.x >> 6;  // 16 rowblocks of 1024 rows
  int ch = blockIdx.x & 63;  // 64 chunks
  int k0 = ch << 7;          // CPC codes per chunk
  if (tid < CPC) {
    const float4* src = (const float4*)(ws + WS_CBN + (size_t)(k0 + tid) * 8);
    scb[tid * 2]     = src[0];
    scb[tid * 2 + 1] = src[1];
    sch[tid] = ws[WS_C2 + k0 + tid];
  }
  int rbase = (rb << 10) + tid;  // rows rbase + j*256, j<4

  float4 m0a, m0b, m1a, m1b, m2a, m2b, m3a, m3b;
  load_enc_neg_norm(ws, rbase,       m0a, m0b);
  load_enc_neg_norm(ws, rbase + 256, m1a, m1b);
  load_enc_neg_norm(ws, rbase + 512, m2a, m2b);
  load_enc_neg_norm(ws, rbase + 768, m3a, m3b);
  float b0 = 3.4e38f, b1 = 3.4e38f, b2 = 3.4e38f, b3 = 3.4e38f;

  __syncthreads();
#pragma unroll 2
  for (int k = 0; k < CPC; k += 2) {
    float4 c00 = scb[2 * k + 0];
    float4 c01 = scb[2 * k + 1];
    float4 c10 = scb[2 * k + 2];
    float4 c11 = scb[2 * k + 3];
    float ca = sch[k];
    float cb = sch[k + 1];
#define STEP2(ma, mb, bj) {                                                   \
    float s0 = score8(ma, mb, c00, c01, ca);                                  \
    float s1 = score8(ma, mb, c10, c11, cb);                                  \
    asm("v_min3_f32 %0, %1, %2, %3" : "=v"(bj) : "v"(bj), "v"(s0), "v"(s1)); }
    STEP2(m0a, m0b, b0)
    STEP2(m1a, m1b, b1)
    STEP2(m2a, m2b, b2)
    STEP2(m3a, m3b, b3)
#undef STEP2
  }
  float* part = ws + WS_PART + (size_t)ch * 16384 + rbase;
  part[0]   = b0;
  part[256] = b1;
  part[512] = b2;
  part[768] = b3;
}

// ---------------- K2b v2: 4 threads per row (256 blocks x 256 = 65536 threads).
// Phase 1: each lane scans 16 chunk-mins; quad shuffle-reduce -> first-min chunk.
// Phase 2: each lane rescans 32 codes of that chunk with the bit-identical DAG;
// quad shuffle-reduce (score, then lower index on tie) -> first-min code.
// Matches reference argmax(-dist) first-min tie order.
__global__ __launch_bounds__(256) void k2b_argmin(float* __restrict__ ws, float* __restrict__ out)
{
  int gtid = blockIdx.x * 256 + threadIdx.x;
  int r = gtid >> 2;
  int sub = gtid & 3;
  const float* part = ws + WS_PART;
  float m = 3.4e38f;
  int cbest = NCH;
  int ch0 = sub << 4;
#pragma unroll 4
  for (int i = 0; i < 16; i++) {
    int ch = ch0 + i;
    float p = part[(size_t)ch * 16384 + r];
    if (p < m) { m = p; cbest = ch; }  // ascending ch within lane => first min
  }
#pragma unroll
  for (int off = 1; off <= 2; off <<= 1) {
    float om = __shfl_xor(m, off);
    int oc = __shfl_xor(cbest, off);
    if (om < m || (om == m && oc < cbest)) { m = om; cbest = oc; }
  }
  float4 ma, mb;
  load_enc_neg_norm(ws, r, ma, mb);
  int base = (cbest << 7) + (sub << 5);  // lane's 32-code slice of winning chunk
  float best = 3.4e38f;
  int bi = 0x7fffffff;
#pragma unroll 4
  for (int k = 0; k < 32; k++) {
    const float4* cp = (const float4*)(ws + WS_CBN + (size_t)(base + k) * 8);
    float4 c0 = cp[0], c1 = cp[1];
    float cc = ws[WS_C2 + base + k];
    float s = score8(ma, mb, c0, c1, cc);
    if (s < best) { best = s; bi = base + k; }  // first min within slice
  }
#pragma unroll
  for (int off = 1; off <= 2; off <<= 1) {
    float os = __shfl_xor(best, off);
    int oi = __shfl_xor(bi, off);
    if (os < best || (os == best && oi < bi)) { best = os; bi = oi; }
  }
  if (sub == 0) {
    out[IDX_OFS + r] = (float)bi;
    ((int*)(ws + WS_IDXI))[r] = bi;
  }
}

// ---------------- K3: out = w_out @ codebook[idx] + b_out (HBM write-bound) -----
__global__ __launch_bounds__(256) void k3_proj_out(
    const float* __restrict__ codebook, const float* __restrict__ w_out,
    const float* __restrict__ b_out, const float* __restrict__ ws,
    float* __restrict__ out)
{
  int bx = blockIdx.x;
  int b = bx >> 7;
  int th = (bx >> 6) & 1;
  int dt = bx & 63;
  int tid = threadIdx.x;
  int t = (th << 10) + (tid << 2);
  const int* idxp = (const int*)(ws + WS_IDXI);
  int4 id = *(const int4*)(idxp + b * TTT + t);
  const float4* cbp = (const float4*)codebook;
  float4 c00 = cbp[(size_t)id.x * 2], c01 = cbp[(size_t)id.x * 2 + 1];
  float4 c10 = cbp[(size_t)id.y * 2], c11 = cbp[(size_t)id.y * 2 + 1];
  float4 c20 = cbp[(size_t)id.z * 2], c21 = cbp[(size_t)id.z * 2 + 1];
  float4 c30 = cbp[(size_t)id.w * 2], c31 = cbp[(size_t)id.w * 2 + 1];
  int d0 = dt << 4;
#pragma unroll 4
  for (int dd = 0; dd < 16; dd++) {
    int d = d0 + dd;
    const float* wr = w_out + (size_t)d * 8;
    float w0 = wr[0], w1 = wr[1], w2 = wr[2], w3 = wr[3];
    float w4 = wr[4], w5 = wr[5], w6 = wr[6], w7 = wr[7];
    float bb = b_out[d];
#define DOT8(lo, hi)                                                          \
    fmaf(w7, hi.w, fmaf(w6, hi.z, fmaf(w5, hi.y, fmaf(w4, hi.x,              \
    fmaf(w3, lo.w, fmaf(w2, lo.z, fmaf(w1, lo.y, fmaf(w0, lo.x, bb))))))))
    float4 r;
    r.x = DOT8(c00, c01);
    r.y = DOT8(c10, c11);
    r.z = DOT8(c20, c21);
    r.w = DOT8(c30, c31);
#undef DOT8
    *(float4*)(out + OUT_OFS + ((size_t)b * DIN + d) * TTT + t) = r;
  }
}

extern "C" void kernel_launch(void* const* d_in, const int* in_sizes, int n_in,
                              void* d_out, int out_size, void* d_ws, size_t ws_size,
                              hipStream_t stream) {
  const float* z        = (const float*)d_in[0];
  const float* w_in     = (const float*)d_in[1];
  const float* b_in     = (const float*)d_in[2];
  const float* w_out    = (const float*)d_in[3];
  const float* b_out    = (const float*)d_in[4];
  const float* codebook = (const float*)d_in[5];
  float* out = (float*)d_out;
  float* ws  = (float*)d_ws;

  k0_prep<<<dim3(37), dim3(256), 0, stream>>>(w_in, codebook, ws, out);
  k1_proj_in<<<dim3(256), dim3(512), 0, stream>>>(z, b_in, ws, out);
  k2_scan<<<dim3(1024), dim3(256), 0, stream>>>(ws);
  k2b_argmin<<<dim3(256), dim3(256), 0, stream>>>(ws, out);
  k3_proj_out<<<dim3(1024), dim3(256), 0, stream>>>(codebook, w_out, b_out, ws, out);
}